// Round 2
// baseline (2336.658 us; speedup 1.0000x reference)
//
#include <hip/hip_runtime.h>

// Encoder: 2-layer LSTM (H1=64, H2=32, IN=2), B=512, T=4096, + FC [32->16].
// R14: de-stack waves (contention theory). 128-thread blocks, 2 SYMMETRIC
// waves, 1 wave/SIMD expected (512 blocks x 2 waves = 4 waves/CU):
//  - each wave: L1 half (32 units, pair-split K, verbatim R13 code) +
//    L2 half restructured: each lane owns ONE full L2 gate-row (K=96,
//    12x dot8 in 4 parallel partial chains, no DPP K-reduce, no selects),
//    quad-broadcast of activated gates as before. Same total fdot2/step,
//    now on 2 uncontended waves; barrier spans 2 symmetric waves (no skew).
//  - keeps R13's lightweight barrier (lgkmcnt-only) + pre-scaled gate
//    weights (i/f/o rows * -log2e, g rows * -2log2e), x fp16 LDS double
//    buffer staged by wave 0, L2 lagging L1 by one step, h double-buffer.

#define TT 4096
#define BB 512

typedef float    f4  __attribute__((ext_vector_type(4)));
typedef int      i4  __attribute__((ext_vector_type(4)));
typedef _Float16 h2v __attribute__((ext_vector_type(2)));
typedef _Float16 h8  __attribute__((ext_vector_type(8)));   // 4 VGPRs

__device__ __forceinline__ float fexp2(float x){ return __builtin_amdgcn_exp2f(x); }
__device__ __forceinline__ float frcp (float x){ return __builtin_amdgcn_rcpf(x); }
// logistic on a PRE-SCALED argument (scale folded into weights/bias).
__device__ __forceinline__ float lgs  (float p){ return frcp(1.0f + fexp2(p)); }
__device__ __forceinline__ float tanh_(float x){ return 1.0f - 2.0f * frcp(1.0f + fexp2(x * 2.8853900817779268f)); }

// Lightweight barrier: LDS-drain only; leaves global prefetch in flight.
#define BARRIER() asm volatile("s_waitcnt lgkmcnt(0)\n\ts_barrier" ::: "memory")

// DPP move. 0xB1=[1,0,3,2]; 0x4E=[2,3,0,1]; 0x00/0x55/0xAA/0xFF = quad bcast.
template<int CTRL>
__device__ __forceinline__ float qperm(float v){
  const int s = __builtin_bit_cast(int, v);
  return __builtin_bit_cast(float, __builtin_amdgcn_update_dpp(s, s, CTRL, 0xF, 0xF, true));
}
__device__ __forceinline__ h2v bch(int s){ return __builtin_bit_cast(h2v, s); }
__device__ __forceinline__ float dot8(h8 a, i4 bi, float c){
  const i4 ai = __builtin_bit_cast(i4, a);
  c = __builtin_amdgcn_fdot2(bch(ai.x), bch(bi.x), c, false);
  c = __builtin_amdgcn_fdot2(bch(ai.y), bch(bi.y), c, false);
  c = __builtin_amdgcn_fdot2(bch(ai.z), bch(bi.z), c, false);
  c = __builtin_amdgcn_fdot2(bch(ai.w), bch(bi.w), c, false);
  return c;
}
__device__ __forceinline__ float fdh(int a, int b, float c){
  return __builtin_amdgcn_fdot2(bch(a), bch(b), c, false);
}
__device__ __forceinline__ int pack16(float a, float b){
  h2v p; p.x = (_Float16)a; p.y = (_Float16)b;
  return __builtin_bit_cast(int, p);
}
__device__ __forceinline__ h8 ldh8s(const float* p, float s){
  const f4 a = ((const f4*)p)[0], b = ((const f4*)p)[1];
  h8 r;
  r[0]=(_Float16)(a.x*s); r[1]=(_Float16)(a.y*s); r[2]=(_Float16)(a.z*s); r[3]=(_Float16)(a.w*s);
  r[4]=(_Float16)(b.x*s); r[5]=(_Float16)(b.y*s); r[6]=(_Float16)(b.z*s); r[7]=(_Float16)(b.w*s);
  return r;
}

extern "C" __global__ __launch_bounds__(128) void lstm_enc_kernel(
    const float* __restrict__ x,
    const float* __restrict__ Wih1, const float* __restrict__ Whh1,
    const float* __restrict__ bih1, const float* __restrict__ bhh1,
    const float* __restrict__ Wih2, const float* __restrict__ Whh2,
    const float* __restrict__ bih2, const float* __restrict__ bhh2,
    const float* __restrict__ Wfc,  const float* __restrict__ bfc,
    float* __restrict__ out)
{
    const int tid = threadIdx.x;
    const int l   = tid & 63;
    const int wv  = __builtin_amdgcn_readfirstlane(tid >> 6);   // 0 or 1
    const int b   = blockIdx.x;

    // hh[buf][0:64) = h1 halves, hh[buf][64:96) = h2 halves. Contiguous:
    // hh[0][k+96] aliases hh[1][k] (used for immediate-offset writes).
    __shared__ __align__(16) _Float16 hh[2][96];
    __shared__ int xs[2][64];     // packed-fp16 x, one chunk (64 steps) each

    // ---- role indices: both waves symmetric ----
    const int u1 = wv * 32 + (l >> 1);   // L1: pair = unit (this wave's 32 units)
    const int s1 = l & 1;                // L1 K-half
    const int u2 = wv * 16 + (l >> 2);   // L2: quad = unit (this wave's 16 units)
    const int g2 = l & 3;                // L2: own gate (i,f,g,o)

    // ---- L1 weights: 16 shared h8 (verbatim R13 scheme), PRE-SCALED ----
    h8 w00,w01,w02,w03, w10,w11,w12,w13, w20,w21,w22,w23, w30,w31,w32,w33;
    float bb0,bb1,bb2,bb3;
    int wxp0,wxp1,wxp2,wxp3;      // packed (wx0,wx1) per gate, s1==0 lanes only

#define LW1(G, W0,W1,W2,W3, BB_, WXP_) { \
    const float kS = ((G)==2) ? -2.8853900817779268f : -1.4426950408889634f; \
    const int rg1 = (G)*64 + u1; \
    const float* a1 = Whh1 + rg1*64 + 32*s1; \
    W0 = ldh8s(a1+ 0,kS); W1 = ldh8s(a1+ 8,kS); \
    W2 = ldh8s(a1+16,kS); W3 = ldh8s(a1+24,kS); \
    const float bbv = (bih1[rg1] + bhh1[rg1]) * kS; \
    BB_  = s1 ? 0.f : bbv; \
    WXP_ = (!s1) ? pack16(Wih1[rg1*2]*kS, Wih1[rg1*2+1]*kS) : 0; }

    LW1(0, w00,w01,w02,w03, bb0, wxp0)
    LW1(1, w10,w11,w12,w13, bb1, wxp1)
    LW1(2, w20,w21,w22,w23, bb2, wxp2)
    LW1(3, w30,w31,w32,w33, bb3, wxp3)
#undef LW1

    // ---- L2 weights: lane owns full row r2row = g2*32 + u2, K = 64+32 ----
    const float kS2 = (g2 == 2) ? -2.8853900817779268f : -1.4426950408889634f;
    const int r2row = g2 * 32 + u2;
    const float* i2p = Wih2 + r2row * 64;
    const float* h2p = Whh2 + r2row * 32;
    const h8 z0 = ldh8s(i2p+ 0,kS2), z1 = ldh8s(i2p+ 8,kS2),
             z2 = ldh8s(i2p+16,kS2), z3 = ldh8s(i2p+24,kS2),
             z4 = ldh8s(i2p+32,kS2), z5 = ldh8s(i2p+40,kS2),
             z6 = ldh8s(i2p+48,kS2), z7 = ldh8s(i2p+56,kS2),
             z8 = ldh8s(h2p+ 0,kS2), z9 = ldh8s(h2p+ 8,kS2),
             z10= ldh8s(h2p+16,kS2), z11= ldh8s(h2p+24,kS2);
    const float bb2q = (bih2[r2row] + bhh2[r2row]) * kS2;

    const float sf  = (float)s1;                 // L1 tanh blend (g-row on odd lane)
    const float g2t = (g2 == 2) ? 1.f : 0.f;     // L2 tanh blend (own g-row)

    // ---- precomputed LDS access pointers (immediate offsets do the rest) ----
    const i4* hRd = ((const i4*)hh[0]) + 4*s1;   // L1: this lane's K-half
    const i4* qRd =  (const i4*)hh[0];           // L2: uniform, full 96 fp16
    _Float16* hWr = &hh[0][u1];
    _Float16* qWr = &hh[0][64 + u2];

    // ---- x staging (wave 0 only): packed fp16, double-buffered chunks ----
    const float2* xb2 = (const float2*)(x + (size_t)b * (TT * 2));
    float2 vxn = make_float2(0.f, 0.f);
    if (wv == 0) {
        const float2 c0 = xb2[l];
        xs[0][l] = pack16(c0.x, c0.y);           // chunk 0
        vxn = xb2[64 + l];                       // chunk 1 in regs
    }
    if (tid < 96) ((int*)hh)[tid] = 0;           // zero both h buffers
    BARRIER();

    float cc1 = 0.f;   // c1 for unit u1 (pair-redundant)
    float cc2 = 0.f;   // c2 for unit u2 (quad-redundant)

#define STEP(T_, L1EN, RO, WO, XH) { \
    if (L1EN) { \
        const int xh_ = (XH); \
        const i4 H0 = hRd[(RO)+0], H1 = hRd[(RO)+1]; \
        const i4 H2 = hRd[(RO)+2], H3 = hRd[(RO)+3]; \
        float a0 = bb0, a1 = bb1, a2 = bb2, a3 = bb3; \
        a0 = dot8(w00,H0,a0); a0 = dot8(w01,H1,a0); a0 = dot8(w02,H2,a0); a0 = dot8(w03,H3,a0); \
        a1 = dot8(w10,H0,a1); a1 = dot8(w11,H1,a1); a1 = dot8(w12,H2,a1); a1 = dot8(w13,H3,a1); \
        a2 = dot8(w20,H0,a2); a2 = dot8(w21,H1,a2); a2 = dot8(w22,H2,a2); a2 = dot8(w23,H3,a2); \
        a3 = dot8(w30,H0,a3); a3 = dot8(w31,H1,a3); a3 = dot8(w32,H2,a3); a3 = dot8(w33,H3,a3); \
        a0 = fdh(wxp0, xh_, a0); a1 = fdh(wxp1, xh_, a1); \
        a2 = fdh(wxp2, xh_, a2); a3 = fdh(wxp3, xh_, a3); \
        a0 += qperm<0xB1>(a0); a1 += qperm<0xB1>(a1); \
        a2 += qperm<0xB1>(a2); a3 += qperm<0xB1>(a3); \
        const float pe0 = s1 ? a2 : a0; \
        const float pe1 = s1 ? a3 : a1; \
        const float sa  = lgs(pe0); \
        const float v0  = fmaf(sf, sa - 1.f, sa); \
        const float v1  = lgs(pe1); \
        const float o0  = qperm<0xB1>(v0); \
        const float o1  = qperm<0xB1>(v1); \
        const float gi = s1 ? o0 : v0, gf = s1 ? o1 : v1; \
        const float gg = s1 ? v0 : o0, go = s1 ? v1 : o1; \
        cc1 = fmaf(gf, cc1, gi * gg); \
        const float h1v = go * tanh_(cc1); \
        if (!s1) hWr[WO] = (_Float16)h1v; \
    } \
    if ((T_) > 0) { \
        const i4 G0 = qRd[(RO)+0], G1 = qRd[(RO)+1], G2 = qRd[(RO)+2]; \
        const i4 G3 = qRd[(RO)+3], G4 = qRd[(RO)+4], G5 = qRd[(RO)+5]; \
        const i4 G6 = qRd[(RO)+6], G7 = qRd[(RO)+7], G8 = qRd[(RO)+8]; \
        const i4 G9 = qRd[(RO)+9], Ga = qRd[(RO)+10], Gb = qRd[(RO)+11]; \
        float p0 = bb2q, p1 = 0.f, p2 = 0.f, p3 = 0.f; \
        p0 = dot8(z0,G0,p0); p0 = dot8(z1,G1,p0); p0 = dot8(z2,G2,p0); \
        p1 = dot8(z3,G3,p1); p1 = dot8(z4,G4,p1); p1 = dot8(z5,G5,p1); \
        p2 = dot8(z6,G6,p2); p2 = dot8(z7,G7,p2); p2 = dot8(z8,G8,p2); \
        p3 = dot8(z9,G9,p3); p3 = dot8(z10,Ga,p3); p3 = dot8(z11,Gb,p3); \
        const float pre = (p0 + p1) + (p2 + p3); \
        const float sv  = lgs(pre); \
        const float act = fmaf(g2t, sv - 1.f, sv); \
        const float i2g = qperm<0x00>(act); \
        const float f2g = qperm<0x55>(act); \
        const float gvg = qperm<0xAA>(act); \
        const float o2g = qperm<0xFF>(act); \
        cc2 = fmaf(f2g, cc2, i2g * gvg); \
        const float h2n = o2g * tanh_(cc2); \
        if (g2 == 0) qWr[WO] = (_Float16)h2n; \
    } \
    BARRIER(); \
}

    for (int c = 0; c < 64; ++c) {
        if (wv == 0) {
            // stage chunk c+1 (held in vxn), prefetch chunk c+2
            if (c + 1 < 64) xs[(c + 1) & 1][l] = pack16(vxn.x, vxn.y);
            if (c + 2 < 64) vxn = xb2[(c + 2) * 64 + l];
        }
        const int* xc = xs[c & 1];
        const int base = c << 6;
        for (int tt = 0; tt < 64; tt += 2) {
            STEP(base + tt,     1, 0,  96, xc[tt])      // rb=0: read hh[0], write hh[1]
            STEP(base + tt + 1, 1, 12, 0,  xc[tt + 1])  // rb=1: read hh[1], write hh[0]
        }
    }
    STEP(TT, 0, 0, 96, 0)   // final L2 step (t=TT-1): read hh[0], write hh[1]
#undef STEP

    // final h2(TT-1) is in hh[1][64:96)
    if (tid < 16) {
        float s = bfc[tid];
        const float* wr = Wfc + tid * 32;
        #pragma unroll
        for (int k = 0; k < 32; ++k) s = fmaf(wr[k], (float)hh[1][64 + k], s);
        out[b * 16 + tid] = s;
    }
}

extern "C" void kernel_launch(void* const* d_in, const int* in_sizes, int n_in,
                              void* d_out, int out_size, void* d_ws, size_t ws_size,
                              hipStream_t stream) {
    const float* x    = (const float*)d_in[0];
    const float* Wih1 = (const float*)d_in[1];
    const float* Whh1 = (const float*)d_in[2];
    const float* bih1 = (const float*)d_in[3];
    const float* bhh1 = (const float*)d_in[4];
    const float* Wih2 = (const float*)d_in[5];
    const float* Whh2 = (const float*)d_in[6];
    const float* bih2 = (const float*)d_in[7];
    const float* bhh2 = (const float*)d_in[8];
    const float* Wfc  = (const float*)d_in[9];
    const float* bfc  = (const float*)d_in[10];

    hipLaunchKernelGGL(lstm_enc_kernel, dim3(BB), dim3(128), 0, stream,
        x, Wih1, Whh1, bih1, bhh1, Wih2, Whh2, bih2, bhh2, Wfc, bfc,
        (float*)d_out);
}

// Round 3
// 1857.250 us; speedup vs baseline: 1.2581x; 1.2581x over previous
//
#include <hip/hip_runtime.h>

// Encoder: 2-layer LSTM (H1=64, H2=32, IN=2), B=512, T=4096, + FC [32->16].
// R15 = R13 (best: 1928us) per-wave code, restructured for SIMD role-mixing:
//  - 512-thread blocks, 2 batch elements per block, 256 blocks (1/CU).
//    Waves: 0,1=L2(b0) 2,3=L1(b0) 4,5=L1(b1) 6,7=L2(b1). With wave i ->
//    SIMD i&3, EVERY SIMD hosts one L1 wave + one L2 wave (R13 stacked two
//    L1 waves on SIMDs 2,3 across its 2 co-resident blocks; the L1-heavy
//    SIMDs set the wall). Critical-SIMD issue ~560 -> ~460 cy/step and
//    heterogeneous stalls interleave.
//  - per-wave code verbatim R13: pair-split L1 (32 units/wave, K halves),
//    quad-split L2 (16 units/wave, K quarters), 16 shared h8 weights with
//    ternary addresses, pre-scaled gates (i/f/o * -log2e, g * -2log2e),
//    lightweight lgkmcnt-only barrier, fp16 x LDS double-buffer staging
//    (waves 0 and 6 stage their own batch element's x).

#define TT 4096
#define BB 512

typedef float    f4  __attribute__((ext_vector_type(4)));
typedef int      i4  __attribute__((ext_vector_type(4)));
typedef _Float16 h2v __attribute__((ext_vector_type(2)));
typedef _Float16 h8  __attribute__((ext_vector_type(8)));   // 4 VGPRs

__device__ __forceinline__ float fexp2(float x){ return __builtin_amdgcn_exp2f(x); }
__device__ __forceinline__ float frcp (float x){ return __builtin_amdgcn_rcpf(x); }
// logistic on a PRE-SCALED argument (scale folded into weights/bias).
__device__ __forceinline__ float lgs  (float p){ return frcp(1.0f + fexp2(p)); }
__device__ __forceinline__ float tanh_(float x){ return 1.0f - 2.0f * frcp(1.0f + fexp2(x * 2.8853900817779268f)); }

// Lightweight barrier: LDS-drain only; leaves global prefetch in flight.
#define BARRIER() asm volatile("s_waitcnt lgkmcnt(0)\n\ts_barrier" ::: "memory")

// DPP move. 0xB1=[1,0,3,2]; 0x4E=[2,3,0,1]; 0x00/0x55/0xAA/0xFF = quad bcast.
template<int CTRL>
__device__ __forceinline__ float qperm(float v){
  const int s = __builtin_bit_cast(int, v);
  return __builtin_bit_cast(float, __builtin_amdgcn_update_dpp(s, s, CTRL, 0xF, 0xF, true));
}
__device__ __forceinline__ h2v bch(int s){ return __builtin_bit_cast(h2v, s); }
__device__ __forceinline__ float dot8(h8 a, i4 bi, float c){
  const i4 ai = __builtin_bit_cast(i4, a);
  c = __builtin_amdgcn_fdot2(bch(ai.x), bch(bi.x), c, false);
  c = __builtin_amdgcn_fdot2(bch(ai.y), bch(bi.y), c, false);
  c = __builtin_amdgcn_fdot2(bch(ai.z), bch(bi.z), c, false);
  c = __builtin_amdgcn_fdot2(bch(ai.w), bch(bi.w), c, false);
  return c;
}
__device__ __forceinline__ float fdh(int a, int b, float c){
  return __builtin_amdgcn_fdot2(bch(a), bch(b), c, false);
}
__device__ __forceinline__ int pack16(float a, float b){
  h2v p; p.x = (_Float16)a; p.y = (_Float16)b;
  return __builtin_bit_cast(int, p);
}
__device__ __forceinline__ h8 ldh8s(const float* p, float s){
  const f4 a = ((const f4*)p)[0], b = ((const f4*)p)[1];
  h8 r;
  r[0]=(_Float16)(a.x*s); r[1]=(_Float16)(a.y*s); r[2]=(_Float16)(a.z*s); r[3]=(_Float16)(a.w*s);
  r[4]=(_Float16)(b.x*s); r[5]=(_Float16)(b.y*s); r[6]=(_Float16)(b.z*s); r[7]=(_Float16)(b.w*s);
  return r;
}

extern "C" __global__ __launch_bounds__(512) void lstm_enc_kernel(
    const float* __restrict__ x,
    const float* __restrict__ Wih1, const float* __restrict__ Whh1,
    const float* __restrict__ bih1, const float* __restrict__ bhh1,
    const float* __restrict__ Wih2, const float* __restrict__ Whh2,
    const float* __restrict__ bih2, const float* __restrict__ bhh2,
    const float* __restrict__ Wfc,  const float* __restrict__ bfc,
    float* __restrict__ out)
{
    const int tid = threadIdx.x;
    const int l   = tid & 63;
    const int wv  = __builtin_amdgcn_readfirstlane(tid >> 6);   // 0..7, scalar
    // role map: waves 0,1 = L2(b0); 2,3 = L1(b0); 4,5 = L1(b1); 6,7 = L2(b1)
    const int be  = (wv >> 2) & 1;                  // batch element within block
    const bool isL1 = (wv >= 2 && wv <= 5);
    const bool stager = (wv == 0 || wv == 6);       // one L2 wave per be stages x
    const int bg  = blockIdx.x * 2 + be;            // global batch index

    // per-be: hh[be][buf][0:64) = h1 halves, [64:96) = h2 halves. Contiguous:
    // hh[be][0][k+96] aliases hh[be][1][k] (immediate-offset writes).
    __shared__ __align__(16) _Float16 hh[2][2][96];
    __shared__ int xs[2][2][64];  // per-be packed-fp16 x, 64-step chunks, dbuf

    // ---- R13 role indices (wv&1 = pair half within role, both be's) ----
    const int u1 = (wv & 1) * 32 + (l >> 1);   // L1: pair = unit
    const int s1 = l & 1;                      // L1 K-half
    const int u2 = (wv & 1) * 16 + (l >> 2);   // L2: quad = unit
    const int s2 = l & 3;                      // L2 K-quarter

    // ---- weights: 16 shared h8 (R13 scheme, ternary addresses), PRE-SCALED ----
    h8 w00,w01,w02,w03, w10,w11,w12,w13, w20,w21,w22,w23, w30,w31,w32,w33;
    float bb0,bb1,bb2,bb3;
    int wxp0,wxp1,wxp2,wxp3;      // packed (wx0,wx1) per gate, s1==0 lanes only

#define LWROW(G, W0,W1,W2,W3, BB_, WXP_) { \
    const float kS = ((G)==2) ? -2.8853900817779268f : -1.4426950408889634f; \
    const int rg1 = (G)*64 + u1; \
    const int rg2 = (G)*32 + u2; \
    const float* a1  = Whh1 + rg1*64 + 32*s1; \
    const float* i2p = Wih2 + rg2*64; \
    const float* h2p = Whh2 + rg2*32; \
    const int f0 = 24*s2, f1 = f0+8, f2c = f0+16; \
    const float* q0 = isL1 ? (a1+ 0) : (f0  < 64 ? i2p+f0  : h2p+f0 -64); \
    const float* q1 = isL1 ? (a1+ 8) : (f1  < 64 ? i2p+f1  : h2p+f1 -64); \
    const float* q2 = isL1 ? (a1+16) : (f2c < 64 ? i2p+f2c : h2p+f2c-64); \
    const float* q3 = isL1 ? (a1+24) : q2; \
    W0 = ldh8s(q0,kS); W1 = ldh8s(q1,kS); W2 = ldh8s(q2,kS); W3 = ldh8s(q3,kS); \
    const float bb1v = (bih1[rg1] + bhh1[rg1]) * kS; \
    const float bb2v = (bih2[rg2] + bhh2[rg2]) * kS; \
    BB_  = isL1 ? (s1 ? 0.f : bb1v) : (s2 ? 0.f : bb2v); \
    WXP_ = (isL1 && !s1) ? pack16(Wih1[rg1*2]*kS, Wih1[rg1*2+1]*kS) : 0; }

    LWROW(0, w00,w01,w02,w03, bb0, wxp0)
    LWROW(1, w10,w11,w12,w13, bb1, wxp1)
    LWROW(2, w20,w21,w22,w23, bb2, wxp2)
    LWROW(3, w30,w31,w32,w33, bb3, wxp3)
#undef LWROW

    const float sf  = (float)s1;                 // L1 tanh blend (g-row on odd lane)
    const float g2t = (s2 == 2) ? 1.f : 0.f;     // L2 tanh blend

    // ---- precomputed LDS access pointers (immediate offsets do the rest) ----
    const i4* hRd = ((const i4*)hh[be][0]) + 4*s1;   // A: [k], B: [12+k]
    const i4* qRd = ((const i4*)hh[be][0]) + 3*s2;
    _Float16* hWr = &hh[be][0][u1];                  // A: [96], B: [0]
    _Float16* qWr = &hh[be][0][64 + u2];

    // ---- x staging (waves 0 and 6): packed fp16, double-buffered chunks ----
    const float2* xb2 = (const float2*)(x + (size_t)bg * (TT * 2));
    float2 vxn = make_float2(0.f, 0.f);
    if (stager) {
        const float2 c0 = xb2[l];
        xs[be][0][l] = pack16(c0.x, c0.y);           // chunk 0
        vxn = xb2[64 + l];                           // chunk 1 in regs
    }
    if (tid < 192) ((int*)hh)[tid] = 0;              // zero all h buffers
    BARRIER();

    float cc = 0.f;   // c1 (L1 lanes) / c2 (L2 lanes)

#define STEP(T_, L1EN, RO, WO, XH) { \
    if (isL1) { \
        if (L1EN) { \
            const int xh_ = (XH); \
            const i4 H0 = hRd[(RO)+0], H1 = hRd[(RO)+1]; \
            const i4 H2 = hRd[(RO)+2], H3 = hRd[(RO)+3]; \
            float r0 = bb0, r1 = bb1, r2 = bb2, r3 = bb3; \
            r0 = dot8(w00,H0,r0); r0 = dot8(w01,H1,r0); r0 = dot8(w02,H2,r0); r0 = dot8(w03,H3,r0); \
            r1 = dot8(w10,H0,r1); r1 = dot8(w11,H1,r1); r1 = dot8(w12,H2,r1); r1 = dot8(w13,H3,r1); \
            r2 = dot8(w20,H0,r2); r2 = dot8(w21,H1,r2); r2 = dot8(w22,H2,r2); r2 = dot8(w23,H3,r2); \
            r3 = dot8(w30,H0,r3); r3 = dot8(w31,H1,r3); r3 = dot8(w32,H2,r3); r3 = dot8(w33,H3,r3); \
            r0 = fdh(wxp0, xh_, r0); r1 = fdh(wxp1, xh_, r1); \
            r2 = fdh(wxp2, xh_, r2); r3 = fdh(wxp3, xh_, r3); \
            r0 += qperm<0xB1>(r0); r1 += qperm<0xB1>(r1); \
            r2 += qperm<0xB1>(r2); r3 += qperm<0xB1>(r3); \
            const float pe0 = s1 ? r2 : r0; \
            const float pe1 = s1 ? r3 : r1; \
            const float sa  = lgs(pe0); \
            const float v0  = fmaf(sf, sa - 1.f, sa); \
            const float v1  = lgs(pe1); \
            const float o0  = qperm<0xB1>(v0); \
            const float o1  = qperm<0xB1>(v1); \
            const float gi = s1 ? o0 : v0, gf = s1 ? o1 : v1; \
            const float gg = s1 ? v0 : o0, go = s1 ? v1 : o1; \
            cc = fmaf(gf, cc, gi * gg); \
            const float h1v = go * tanh_(cc); \
            if (!s1) hWr[WO] = (_Float16)h1v; \
        } \
    } else if ((T_) > 0) { \
        const i4 G0 = qRd[(RO)+0], G1 = qRd[(RO)+1], G2 = qRd[(RO)+2]; \
        float r0 = bb0, r1 = bb1, r2 = bb2, r3 = bb3; \
        r0 = dot8(w00,G0,r0); r0 = dot8(w01,G1,r0); r0 = dot8(w02,G2,r0); \
        r1 = dot8(w10,G0,r1); r1 = dot8(w11,G1,r1); r1 = dot8(w12,G2,r1); \
        r2 = dot8(w20,G0,r2); r2 = dot8(w21,G1,r2); r2 = dot8(w22,G2,r2); \
        r3 = dot8(w30,G0,r3); r3 = dot8(w31,G1,r3); r3 = dot8(w32,G2,r3); \
        r0 += qperm<0xB1>(r0); r0 += qperm<0x4E>(r0); \
        r1 += qperm<0xB1>(r1); r1 += qperm<0x4E>(r1); \
        r2 += qperm<0xB1>(r2); r2 += qperm<0x4E>(r2); \
        r3 += qperm<0xB1>(r3); r3 += qperm<0x4E>(r3); \
        const float pre = (s2==0) ? r0 : (s2==1) ? r1 : (s2==2) ? r2 : r3; \
        const float sv  = lgs(pre); \
        const float act = fmaf(g2t, sv - 1.f, sv); \
        const float i2 = qperm<0x00>(act); \
        const float f2 = qperm<0x55>(act); \
        const float gv = qperm<0xAA>(act); \
        const float o2 = qperm<0xFF>(act); \
        cc = fmaf(f2, cc, i2 * gv); \
        const float h2v_ = o2 * tanh_(cc); \
        if (s2 == 0) qWr[WO] = (_Float16)h2v_; \
    } \
    BARRIER(); \
}

    for (int c = 0; c < 64; ++c) {
        if (stager) {
            // stage chunk c+1 (held in vxn), prefetch chunk c+2
            if (c + 1 < 64) xs[be][(c + 1) & 1][l] = pack16(vxn.x, vxn.y);
            if (c + 2 < 64) vxn = xb2[(c + 2) * 64 + l];
        }
        const int* xc = xs[be][c & 1];
        const int base = c << 6;
        for (int tt = 0; tt < 64; tt += 2) {
            STEP(base + tt,     1, 0,  96, xc[tt])      // rb=0: read hh[.][0], write hh[.][1]
            STEP(base + tt + 1, 1, 12, 0,  xc[tt + 1])  // rb=1: read hh[.][1], write hh[.][0]
        }
    }
    STEP(TT, 0, 0, 96, 0)   // final L2 step (t=TT-1): read hh[.][0], write hh[.][1]
#undef STEP

    // final h2(TT-1) is in hh[be][1][64:96); waves 0 and 6 write their be's FC
    if (stager && l < 16) {
        float s = bfc[l];
        const float* wr = Wfc + l * 32;
        #pragma unroll
        for (int k = 0; k < 32; ++k) s = fmaf(wr[k], (float)hh[be][1][64 + k], s);
        out[bg * 16 + l] = s;
    }
}

extern "C" void kernel_launch(void* const* d_in, const int* in_sizes, int n_in,
                              void* d_out, int out_size, void* d_ws, size_t ws_size,
                              hipStream_t stream) {
    const float* x    = (const float*)d_in[0];
    const float* Wih1 = (const float*)d_in[1];
    const float* Whh1 = (const float*)d_in[2];
    const float* bih1 = (const float*)d_in[3];
    const float* bhh1 = (const float*)d_in[4];
    const float* Wih2 = (const float*)d_in[5];
    const float* Whh2 = (const float*)d_in[6];
    const float* bih2 = (const float*)d_in[7];
    const float* bhh2 = (const float*)d_in[8];
    const float* Wfc  = (const float*)d_in[9];
    const float* bfc  = (const float*)d_in[10];

    hipLaunchKernelGGL(lstm_enc_kernel, dim3(BB / 2), dim3(512), 0, stream,
        x, Wih1, Whh1, bih1, bhh1, Wih2, Whh2, bih2, bhh2, Wfc, bfc,
        (float*)d_out);
}

// Round 4
// 1556.444 us; speedup vs baseline: 1.5013x; 1.1933x over previous
//
#include <hip/hip_runtime.h>

// Encoder: 2-layer LSTM (H1=64, H2=32, IN=2), B=512, T=4096, + FC [32->16].
// R16: BARRIER-FREE recurrence (structural rewrite).
//  - One wave owns ALL of L1 for a batch element: lane u computes gates
//    i,f,g,o of unit u over full K=64 (32 dot8 = 128 fdot2). h1 exchange is
//    wave-internal: ds_write_b16 -> lgkmcnt -> 8x uniform (broadcast)
//    ds_read_b128. NO s_barrier in the recurrence loop.
//  - One wave owns ALL of L2: lane = (unit u=l&31, half hf=l>>5); hf=0 does
//    rows i,f; hf=1 does g,o; full K=96 (24 dot8). Gate exchange via one
//    __shfl_xor(32) pair; h2 ring is wave-internal LDS.
//  - L1 -> L2 decoupled by a 128-step h1 ring (2 chunks x 64 steps): L2
//    lags L1 by one chunk; ONE s_barrier per 64-step phase (65 total,
//    vs 4097 in R15). L2 wave also stages x chunks (packed fp16).
//  - Block = 256 thr = {L1(b0), L2(b0), L1(b1), L2(b1)} -> 1 wave/SIMD,
//    grid 256 (1 block/CU). Pre-scaled gates kept (i/f/o * -log2e,
//    g * -2log2e). Weights fully resident: L1 wave 32 h8, L2 wave 24 h8.

#define TT 4096
#define BB 512
#define NCH 64   // chunks of 64 steps

typedef float    f4  __attribute__((ext_vector_type(4)));
typedef int      i4  __attribute__((ext_vector_type(4)));
typedef _Float16 h2v __attribute__((ext_vector_type(2)));
typedef _Float16 h8  __attribute__((ext_vector_type(8)));   // 4 VGPRs

__device__ __forceinline__ float fexp2(float x){ return __builtin_amdgcn_exp2f(x); }
__device__ __forceinline__ float frcp (float x){ return __builtin_amdgcn_rcpf(x); }
// logistic on a PRE-SCALED argument (scale folded into weights/bias).
__device__ __forceinline__ float lgs  (float p){ return frcp(1.0f + fexp2(p)); }
__device__ __forceinline__ float tanh_(float x){ return 1.0f - 2.0f * frcp(1.0f + fexp2(x * 2.8853900817779268f)); }

// Lightweight barrier: LDS-drain only; leaves global prefetch in flight.
#define BARRIER() asm volatile("s_waitcnt lgkmcnt(0)\n\ts_barrier" ::: "memory")

__device__ __forceinline__ h2v bch(int s){ return __builtin_bit_cast(h2v, s); }
__device__ __forceinline__ float dot8(h8 a, i4 bi, float c){
  const i4 ai = __builtin_bit_cast(i4, a);
  c = __builtin_amdgcn_fdot2(bch(ai.x), bch(bi.x), c, false);
  c = __builtin_amdgcn_fdot2(bch(ai.y), bch(bi.y), c, false);
  c = __builtin_amdgcn_fdot2(bch(ai.z), bch(bi.z), c, false);
  c = __builtin_amdgcn_fdot2(bch(ai.w), bch(bi.w), c, false);
  return c;
}
__device__ __forceinline__ float fdh(int a, int b, float c){
  return __builtin_amdgcn_fdot2(bch(a), bch(b), c, false);
}
__device__ __forceinline__ int pack16(float a, float b){
  h2v p; p.x = (_Float16)a; p.y = (_Float16)b;
  return __builtin_bit_cast(int, p);
}
__device__ __forceinline__ h8 ldh8s(const float* p, float s){
  const f4 a = ((const f4*)p)[0], b = ((const f4*)p)[1];
  h8 r;
  r[0]=(_Float16)(a.x*s); r[1]=(_Float16)(a.y*s); r[2]=(_Float16)(a.z*s); r[3]=(_Float16)(a.w*s);
  r[4]=(_Float16)(b.x*s); r[5]=(_Float16)(b.y*s); r[6]=(_Float16)(b.z*s); r[7]=(_Float16)(b.w*s);
  return r;
}

extern "C" __global__ __launch_bounds__(256, 1) void lstm_enc_kernel(
    const float* __restrict__ x,
    const float* __restrict__ Wih1, const float* __restrict__ Whh1,
    const float* __restrict__ bih1, const float* __restrict__ bhh1,
    const float* __restrict__ Wih2, const float* __restrict__ Whh2,
    const float* __restrict__ bih2, const float* __restrict__ bhh2,
    const float* __restrict__ Wfc,  const float* __restrict__ bfc,
    float* __restrict__ out)
{
    const int tid = threadIdx.x;
    const int l   = tid & 63;
    const int wv  = __builtin_amdgcn_readfirstlane(tid >> 6);   // 0..3
    const int be  = wv >> 1;                   // batch element in block
    const bool isL1 = ((wv & 1) == 0);         // waves 0,2 = L1; 1,3 = L2
    const int bg  = blockIdx.x * 2 + be;       // global batch index

    // h1 ring: 128 steps (2 chunks x 64), row t%128 = h1(t) as 64 fp16.
    __shared__ __align__(16) _Float16 ring[2][128][64];   // 32 KB
    __shared__ __align__(16) _Float16 h2r[2][2][32];      // h2 slots (t&1)
    __shared__ int xs[2][2][64];                          // packed-fp16 x

    const float kSs = -1.4426950408889634f;   // sigmoid pre-scale
    const float kSg = -2.8853900817779268f;   // tanh-form pre-scale

    if (isL1) {
        // ------------------- L1 wave: lane u = l owns unit u -------------------
        h8 wi[8], wf[8], wg[8], wo[8];
        const int ri = l, rf = 64 + l, rg = 128 + l, ro = 192 + l;
        #pragma unroll
        for (int j = 0; j < 8; ++j) {
            wi[j] = ldh8s(Whh1 + ri*64 + j*8, kSs);
            wf[j] = ldh8s(Whh1 + rf*64 + j*8, kSs);
            wg[j] = ldh8s(Whh1 + rg*64 + j*8, kSg);
            wo[j] = ldh8s(Whh1 + ro*64 + j*8, kSs);
        }
        const int wxi = pack16(Wih1[ri*2]*kSs, Wih1[ri*2+1]*kSs);
        const int wxf = pack16(Wih1[rf*2]*kSs, Wih1[rf*2+1]*kSs);
        const int wxg = pack16(Wih1[rg*2]*kSg, Wih1[rg*2+1]*kSg);
        const int wxo = pack16(Wih1[ro*2]*kSs, Wih1[ro*2+1]*kSs);
        const float bi_ = (bih1[ri] + bhh1[ri]) * kSs;
        const float bf_ = (bih1[rf] + bhh1[rf]) * kSs;
        const float bg_ = (bih1[rg] + bhh1[rg]) * kSg;
        const float bo_ = (bih1[ro] + bhh1[ro]) * kSs;

        if (l < 32) ((int*)&ring[be][127][0])[l] = 0;   // h1(-1) = 0
        BARRIER();

        float cc = 0.f;
        _Float16* rw = &ring[be][0][0];
        const i4* rd = (const i4*)&ring[be][0][0];      // 8 i4 per row

#define L1S(PR, CR, XV) { \
    const i4* Hp = rd + (PR)*8; \
    i4 H[8]; \
    _Pragma("unroll") for (int j = 0; j < 8; ++j) H[j] = Hp[j]; \
    float ai = bi_, af = bf_, ag = bg_, ao = bo_; \
    _Pragma("unroll") for (int j = 0; j < 8; ++j) { \
        ai = dot8(wi[j], H[j], ai); af = dot8(wf[j], H[j], af); \
        ag = dot8(wg[j], H[j], ag); ao = dot8(wo[j], H[j], ao); } \
    const int xv_ = (XV); \
    ai = fdh(wxi, xv_, ai); af = fdh(wxf, xv_, af); \
    ag = fdh(wxg, xv_, ag); ao = fdh(wxo, xv_, ao); \
    const float gi = lgs(ai), gf = lgs(af), go = lgs(ao); \
    const float gg = fmaf(2.f, lgs(ag), -1.f); \
    cc = fmaf(gf, cc, gi * gg); \
    rw[(CR)*64 + l] = (_Float16)(go * tanh_(cc)); }

        #pragma unroll 1
        for (int c = 0; c <= NCH; ++c) {
            if (c < NCH) {
                const int base = (c & 1) * 64;
                const int p0 = (base ^ 64) + 63;   // last row of other chunk
                const int* xc = xs[be][c & 1];
                L1S(p0, base, xc[0])
                #pragma unroll 2
                for (int s = 1; s < 64; ++s) { L1S(base + s - 1, base + s, xc[s]) }
            }
            BARRIER();
        }
#undef L1S
    } else {
        // --------- L2 wave: lane = (u = l&31, hf = l>>5); rows (i,f)|(g,o) ---------
        const int u = l & 31, hf = l >> 5;
        const float hff = (float)hf;
        const int rA = hf * 64 + u;        // i (hf=0) or g (hf=1)
        const int rB = hf * 64 + 32 + u;   // f (hf=0) or o (hf=1)
        const float kA = hf ? kSg : kSs;
        h8 wa[12], wb[12];
        #pragma unroll
        for (int j = 0; j < 8; ++j) {
            wa[j] = ldh8s(Wih2 + rA*64 + j*8, kA);
            wb[j] = ldh8s(Wih2 + rB*64 + j*8, kSs);
        }
        #pragma unroll
        for (int j = 0; j < 4; ++j) {
            wa[8+j] = ldh8s(Whh2 + rA*32 + j*8, kA);
            wb[8+j] = ldh8s(Whh2 + rB*32 + j*8, kSs);
        }
        const float ba_ = (bih2[rA] + bhh2[rA]) * kA;
        const float bb_ = (bih2[rB] + bhh2[rB]) * kSs;

        if (l < 16) ((int*)&h2r[be][1][0])[l] = 0;      // h2(-1) = 0
        // stage x chunk 0, prefetch chunk 1
        const float2* xb2 = (const float2*)(x + (size_t)bg * (TT * 2));
        {
            const float2 c0 = xb2[l];
            xs[be][0][l] = pack16(c0.x, c0.y);
        }
        float2 vxn = xb2[64 + l];
        BARRIER();

        float c2 = 0.f;
        const i4* rdh = (const i4*)&ring[be][0][0];
        const i4* g0 = (const i4*)&h2r[be][0][0];
        const i4* g1 = (const i4*)&h2r[be][1][0];
        _Float16* q0 = &h2r[be][0][0];
        _Float16* q1 = &h2r[be][1][0];

#define L2S(S, GR, QW) { \
    const i4* Hp = rc + (S)*8; \
    i4 H[8]; \
    _Pragma("unroll") for (int j = 0; j < 8; ++j) H[j] = Hp[j]; \
    i4 G[4]; \
    _Pragma("unroll") for (int j = 0; j < 4; ++j) G[j] = (GR)[j]; \
    float pa = ba_, pb = bb_; \
    _Pragma("unroll") for (int j = 0; j < 8; ++j) { \
        pa = dot8(wa[j], H[j], pa); pb = dot8(wb[j], H[j], pb); } \
    _Pragma("unroll") for (int j = 0; j < 4; ++j) { \
        pa = dot8(wa[8+j], G[j], pa); pb = dot8(wb[8+j], G[j], pb); } \
    const float sa = lgs(pa); \
    const float va = fmaf(hff, sa - 1.f, sa);   /* i or tanh-g */ \
    const float vb = lgs(pb);                   /* f or o      */ \
    const float oa = __shfl_xor(va, 32); \
    const float ob = __shfl_xor(vb, 32); \
    const float gi = hf ? oa : va, gf = hf ? ob : vb; \
    const float gg = hf ? va : oa, go = hf ? vb : ob; \
    c2 = fmaf(gf, c2, gi * gg); \
    const float h2n = go * tanh_(c2); \
    if (!hf) (QW)[u] = (_Float16)h2n; }

        #pragma unroll 1
        for (int c = 0; c <= NCH; ++c) {
            // stage chunk c+1 (in vxn), prefetch chunk c+2
            if (c + 1 < NCH) xs[be][(c + 1) & 1][l] = pack16(vxn.x, vxn.y);
            if (c + 2 < NCH) vxn = xb2[(c + 2) * 64 + l];
            if (c > 0) {
                const i4* rc = rdh + ((c - 1) & 1) * 64 * 8;   // chunk c-1 rows
                // tau = (c-1)*64 + s; tau even: write slot0, read slot1
                for (int s = 0; s < 64; s += 2) {
                    L2S(s,     g1, q0)
                    L2S(s + 1, g0, q1)
                }
            }
            BARRIER();
        }
#undef L2S

        // final h2(TT-1) in h2r[be][1] (4095 is odd -> slot 1)
        if (l < 16) {
            float sum = bfc[l];
            const float* wr = Wfc + l * 32;
            #pragma unroll
            for (int k = 0; k < 32; ++k) sum = fmaf(wr[k], (float)h2r[be][1][k], sum);
            out[bg * 16 + l] = sum;
        }
    }
}

extern "C" void kernel_launch(void* const* d_in, const int* in_sizes, int n_in,
                              void* d_out, int out_size, void* d_ws, size_t ws_size,
                              hipStream_t stream) {
    const float* x    = (const float*)d_in[0];
    const float* Wih1 = (const float*)d_in[1];
    const float* Whh1 = (const float*)d_in[2];
    const float* bih1 = (const float*)d_in[3];
    const float* bhh1 = (const float*)d_in[4];
    const float* Wih2 = (const float*)d_in[5];
    const float* Whh2 = (const float*)d_in[6];
    const float* bih2 = (const float*)d_in[7];
    const float* bhh2 = (const float*)d_in[8];
    const float* Wfc  = (const float*)d_in[9];
    const float* bfc  = (const float*)d_in[10];

    hipLaunchKernelGGL(lstm_enc_kernel, dim3(BB / 2), dim3(256), 0, stream,
        x, Wih1, Whh1, bih1, bhh1, Wih2, Whh2, bih2, bhh2, Wfc, bfc,
        (float*)d_out);
}